// Round 10
// baseline (8009.113 us; speedup 1.0000x reference)
//
#include <hip/hip_runtime.h>

#define TT 200
#define SS 1024
#define DD 512
#define VV 30
#define BB 64
#define BBDD (BB*DD)              // 32768
#define CNBLK 192                 // persistent chain blocks

// ---- ws layout: uints first (barrier slots), then floats ----
#define WS_GSLOT 0                         // [192*32] uints
#define WS_GBF   (192*32)                  // [192*32] uints
#define WS_SLOTS_UINTS (2*192*32)          // 12288
#define WS_H0    12288                     // [2][64][512] floats
#define WS_GI    (WS_H0 + 2*BBDD)          // [2][1536][64]
#define WS_H1A   (WS_GI + 2*1536*64)       // [200][64][512]
#define WS_CALL  (WS_H1A + 200*BBDD)       // [200][64][512]

typedef __attribute__((ext_vector_type(4))) float f4;

__device__ __forceinline__ float dot4(f4 a, f4 b) {
  return a.x*b.x + a.y*b.y + a.z*b.z + a.w*b.w;
}
__device__ __forceinline__ float sigmoidf_(float x) { return 1.f/(1.f + __expf(-x)); }

__device__ __forceinline__ void gl_lds16(const void* g, void* l) {
  __builtin_amdgcn_global_load_lds(
      (const __attribute__((address_space(1))) unsigned int*)g,
      (__attribute__((address_space(3))) unsigned int*)l,
      16, 0, 0);
}

// ---- plain async global [64][512] -> LDS [64][516] ----
__device__ __forceinline__ void stage64(const float* src, float* TILE, int wv, int lane) {
  #pragma unroll
  for (int rr = 0; rr < 8; ++rr) {
    const int row = wv*8 + rr;
    const float* g = src + (size_t)row*DD + lane*4;
    gl_lds16(g,       TILE + row*516);
    gl_lds16(g + 256, TILE + row*516 + 256);
  }
}

// ======== coherent (agent-scope, L2-bypass) helpers — for persistent chain ========
__device__ __forceinline__ void coh_store1(float* p, float v) {
  asm volatile("global_store_dword %0, %1, off sc0 sc1" :: "v"(p), "v"(v) : "memory");
}
__device__ __forceinline__ void coh_load3(const float* p0, const float* p1, const float* p2,
                                          float& r0, float& r1, float& r2) {
  asm volatile(
    "global_load_dword %0, %3, off sc0 sc1\n\t"
    "global_load_dword %1, %4, off sc0 sc1\n\t"
    "global_load_dword %2, %5, off sc0 sc1\n\t"
    "s_waitcnt vmcnt(0)"
    : "=&v"(r0), "=&v"(r1), "=&v"(r2)
    : "v"(p0), "v"(p1), "v"(p2) : "memory");
}
__device__ __forceinline__ void coh_load8x4(const float* g, int stridef, f4 (&r)[8]) {
  const float *a1 = g +   (size_t)stridef, *a2 = g + 2*(size_t)stridef,
              *a3 = g + 3*(size_t)stridef, *a4 = g + 4*(size_t)stridef,
              *a5 = g + 5*(size_t)stridef, *a6 = g + 6*(size_t)stridef,
              *a7 = g + 7*(size_t)stridef;
  asm volatile(
    "global_load_dwordx4 %0, %8, off sc0 sc1\n\t"
    "global_load_dwordx4 %1, %9, off sc0 sc1\n\t"
    "global_load_dwordx4 %2, %10, off sc0 sc1\n\t"
    "global_load_dwordx4 %3, %11, off sc0 sc1\n\t"
    "global_load_dwordx4 %4, %12, off sc0 sc1\n\t"
    "global_load_dwordx4 %5, %13, off sc0 sc1\n\t"
    "global_load_dwordx4 %6, %14, off sc0 sc1\n\t"
    "global_load_dwordx4 %7, %15, off sc0 sc1\n\t"
    "s_waitcnt vmcnt(0)"
    : "=&v"(r[0]), "=&v"(r[1]), "=&v"(r[2]), "=&v"(r[3]),
      "=&v"(r[4]), "=&v"(r[5]), "=&v"(r[6]), "=&v"(r[7])
    : "v"(g), "v"(a1), "v"(a2), "v"(a3), "v"(a4), "v"(a5), "v"(a6), "v"(a7)
    : "memory");
}
// coherent reg-staged copy: global [64][512] -> LDS [64][516]
__device__ __forceinline__ void stage64_coh(const float* src, float* TILE, int tid) {
  f4 r[8];
  const int c4 = (tid & 127) * 4;
  const int rb = tid >> 7;
  coh_load8x4(src + (size_t)tid*4, 2048, r);
  #pragma unroll
  for (int k = 0; k < 8; ++k) *(f4*)&TILE[(rb + 4*k)*516 + c4] = r[k];
  coh_load8x4(src + (size_t)tid*4 + 8*2048, 2048, r);
  #pragma unroll
  for (int k = 0; k < 8; ++k) *(f4*)&TILE[(rb + 4*(k+8))*516 + c4] = r[k];
}

// wave-column GRU dots into LOCAL gate buffer GH[24][64]
__device__ __forceinline__ void wave_dots(const float* TILE, const float* W, const float* bias,
                                          float* GH, int w_id, int wv, int lane) {
  const int c0 = wv*3, c1 = c0+1, c2 = c0+2;
  const int R0 = __builtin_amdgcn_readfirstlane(((c0>>3)<<9) + w_id*8 + (c0&7));
  const int R1 = __builtin_amdgcn_readfirstlane(((c1>>3)<<9) + w_id*8 + (c1&7));
  const int R2 = __builtin_amdgcn_readfirstlane(((c2>>3)<<9) + w_id*8 + (c2&7));
  const f4* w0 = (const f4*)(W + (size_t)R0*DD);
  const f4* w1 = (const f4*)(W + (size_t)R1*DD);
  const f4* w2 = (const f4*)(W + (size_t)R2*DD);
  const f4* hv4 = (const f4*)TILE + (size_t)lane*129;
  float a0=0.f, a1=0.f, a2=0.f;
  #pragma unroll 4
  for (int kq = 0; kq < 128; ++kq) {
    f4 h = hv4[kq];
    a0 += dot4(h, w0[kq]); a1 += dot4(h, w1[kq]); a2 += dot4(h, w2[kq]);
  }
  GH[c0*64 + lane] = a0 + bias[R0];
  GH[c1*64 + lane] = a1 + bias[R1];
  GH[c2*64 + lane] = a2 + bias[R2];
}

// wave-column dots -> GLOBAL gi buffer (plain stores; prologue only)
__device__ __forceinline__ void wave_dots_g(const float* TILE, const float* W, const float* bias,
                                            float* gi, int w_id, int wv, int lane) {
  const int c0 = wv*3, c1 = c0+1, c2 = c0+2;
  const int R0 = __builtin_amdgcn_readfirstlane(((c0>>3)<<9) + w_id*8 + (c0&7));
  const int R1 = __builtin_amdgcn_readfirstlane(((c1>>3)<<9) + w_id*8 + (c1&7));
  const int R2 = __builtin_amdgcn_readfirstlane(((c2>>3)<<9) + w_id*8 + (c2&7));
  const f4* w0 = (const f4*)(W + (size_t)R0*DD);
  const f4* w1 = (const f4*)(W + (size_t)R1*DD);
  const f4* w2 = (const f4*)(W + (size_t)R2*DD);
  const f4* hv4 = (const f4*)TILE + (size_t)lane*129;
  float a0=0.f, a1=0.f, a2=0.f;
  #pragma unroll 4
  for (int kq = 0; kq < 128; ++kq) {
    f4 h = hv4[kq];
    a0 += dot4(h, w0[kq]); a1 += dot4(h, w1[kq]); a2 += dot4(h, w2[kq]);
  }
  gi[(size_t)R0*64 + lane] = a0 + bias[R0];
  gi[(size_t)R1*64 + lane] = a1 + bias[R1];
  gi[(size_t)R2*64 + lane] = a2 + bias[R2];
}

// coherent-store variant (persistent chain)
__device__ __forceinline__ void wave_dots_g_coh(const float* TILE, const float* W, const float* bias,
                                                float* gi, int w_id, int wv, int lane) {
  const int c0 = wv*3, c1 = c0+1, c2 = c0+2;
  const int R0 = __builtin_amdgcn_readfirstlane(((c0>>3)<<9) + w_id*8 + (c0&7));
  const int R1 = __builtin_amdgcn_readfirstlane(((c1>>3)<<9) + w_id*8 + (c1&7));
  const int R2 = __builtin_amdgcn_readfirstlane(((c2>>3)<<9) + w_id*8 + (c2&7));
  const f4* w0 = (const f4*)(W + (size_t)R0*DD);
  const f4* w1 = (const f4*)(W + (size_t)R1*DD);
  const f4* w2 = (const f4*)(W + (size_t)R2*DD);
  const f4* hv4 = (const f4*)TILE + (size_t)lane*129;
  float a0=0.f, a1=0.f, a2=0.f;
  #pragma unroll 4
  for (int kq = 0; kq < 128; ++kq) {
    f4 h = hv4[kq];
    a0 += dot4(h, w0[kq]); a1 += dot4(h, w1[kq]); a2 += dot4(h, w2[kq]);
  }
  coh_store1(&gi[(size_t)R0*64 + lane], a0 + bias[R0]);
  coh_store1(&gi[(size_t)R1*64 + lane], a1 + bias[R1]);
  coh_store1(&gi[(size_t)R2*64 + lane], a2 + bias[R2]);
}

// ---- contention-free broadcast barrier (192 blocks; aggregator bid 0) ----
__device__ __forceinline__ void gridbar(unsigned* gslot, unsigned* gbf,
                                        int bid, int tid, unsigned target) {
  __syncthreads();
  if (tid == 0)
    __hip_atomic_store(&gslot[bid*32], target, __ATOMIC_RELAXED, __HIP_MEMORY_SCOPE_AGENT);
  if (bid == 0) {
    if (tid < 64) {
      for (;;) {
        unsigned v0 = __hip_atomic_load(&gslot[(tid      )*32], __ATOMIC_RELAXED, __HIP_MEMORY_SCOPE_AGENT);
        unsigned v1 = __hip_atomic_load(&gslot[(tid +  64)*32], __ATOMIC_RELAXED, __HIP_MEMORY_SCOPE_AGENT);
        unsigned v2 = __hip_atomic_load(&gslot[(tid + 128)*32], __ATOMIC_RELAXED, __HIP_MEMORY_SCOPE_AGENT);
        if (__all(v0 >= target && v1 >= target && v2 >= target)) break;
        __builtin_amdgcn_s_sleep(2);
      }
    }
    __syncthreads();
    if (tid >= 1 && tid < CNBLK)
      __hip_atomic_store(&gbf[tid*32], target, __ATOMIC_RELAXED, __HIP_MEMORY_SCOPE_AGENT);
  } else if (tid == 0) {
    while (__hip_atomic_load(&gbf[bid*32], __ATOMIC_RELAXED, __HIP_MEMORY_SCOPE_AGENT) < target)
      __builtin_amdgcn_s_sleep(2);
  }
  __syncthreads();
}

// ================= prologue 1: h0(0) =================
__launch_bounds__(512, 1)
__global__ void k_gru0(const float* __restrict__ h0prev, const int* __restrict__ targets,
                       const float* __restrict__ W_ih0, const float* __restrict__ W_hh0,
                       const float* __restrict__ b_ih0, const float* __restrict__ b_hh0,
                       float* __restrict__ h0out, int tokcol) {
  __shared__ float SM[34560];
  float* const TILE = SM;
  float* const GHX  = SM + 33024;
  const int tid = threadIdx.x, bid = blockIdx.x;
  const int lane = tid & 63, wv = tid >> 6;
  stage64(h0prev, TILE, wv, lane);
  __syncthreads();
  wave_dots(TILE, W_hh0, b_hh0, GHX, bid, wv, lane);
  __syncthreads();
  const int dl = tid >> 6, bb = tid & 63, d = bid*8 + dl;
  const int tok = targets[bb*TT + tokcol];
  float gir = W_ih0[(size_t)d*VV + tok]          + b_ih0[d];
  float giz = W_ih0[(size_t)(DD + d)*VV + tok]   + b_ih0[DD + d];
  float gin = W_ih0[(size_t)(2*DD + d)*VV + tok] + b_ih0[2*DD + d];
  float r_ = sigmoidf_(gir + GHX[(0*8 + dl)*64 + bb]);
  float z_ = sigmoidf_(giz + GHX[(1*8 + dl)*64 + bb]);
  float n_ = tanhf(gin + r_*GHX[(2*8 + dl)*64 + bb]);
  float h0old = TILE[bb*516 + d];
  h0out[(size_t)bb*DD + d] = (1.f - z_)*n_ + z_*h0old;
}

// ================= prologue 2: h0(1) [0..63] | GI1(0) [64..127] =================
__launch_bounds__(512, 1)
__global__ void k_pro1(const float* __restrict__ h0buf0, const int* __restrict__ targets,
                       const float* __restrict__ W_ih0, const float* __restrict__ W_hh0,
                       const float* __restrict__ b_ih0, const float* __restrict__ b_hh0,
                       const float* __restrict__ W_ih1, const float* __restrict__ b_ih1,
                       float* __restrict__ h0buf1, float* __restrict__ gibuf0) {
  __shared__ float SM[34560];
  float* const TILE = SM;
  float* const GHX  = SM + 33024;
  const int tid = threadIdx.x, bid = blockIdx.x;
  const int lane = tid & 63, wv = tid >> 6;
  stage64(h0buf0, TILE, wv, lane);
  __syncthreads();
  if (bid < 64) {
    wave_dots(TILE, W_hh0, b_hh0, GHX, bid, wv, lane);
    __syncthreads();
    const int dl = tid >> 6, bb = tid & 63, d = bid*8 + dl;
    const int tok = targets[bb*TT + 0];
    float gir = W_ih0[(size_t)d*VV + tok]          + b_ih0[d];
    float giz = W_ih0[(size_t)(DD + d)*VV + tok]   + b_ih0[DD + d];
    float gin = W_ih0[(size_t)(2*DD + d)*VV + tok] + b_ih0[2*DD + d];
    float r_ = sigmoidf_(gir + GHX[(0*8 + dl)*64 + bb]);
    float z_ = sigmoidf_(giz + GHX[(1*8 + dl)*64 + bb]);
    float n_ = tanhf(gin + r_*GHX[(2*8 + dl)*64 + bb]);
    float h0old = TILE[bb*516 + d];
    h0buf1[(size_t)bb*DD + d] = (1.f - z_)*n_ + z_*h0old;
  } else {
    wave_dots_g(TILE, W_ih1, b_ih1, gibuf0, bid - 64, wv, lane);
  }
}

// ======= fallback chain (r9): h0(t+2) [0..63] | h1(t) [64..127] | GI1(t+1) [128..191] =======
__launch_bounds__(512, 1)
__global__ void k_chain(const float* __restrict__ h0rd, float* __restrict__ h0wr,
                        const float* __restrict__ h1src, float* __restrict__ h1dst,
                        const float* __restrict__ gird, float* __restrict__ giwr,
                        const int* __restrict__ targets,
                        const float* __restrict__ W_ih0, const float* __restrict__ W_hh0,
                        const float* __restrict__ b_ih0, const float* __restrict__ b_hh0,
                        const float* __restrict__ W_hh1, const float* __restrict__ b_hh1,
                        const float* __restrict__ W_ih1, const float* __restrict__ b_ih1,
                        int t) {
  __shared__ float SM[34560];
  float* const TILE = SM;
  float* const GHX  = SM + 33024;
  const int tid = threadIdx.x, bid = blockIdx.x;
  const int lane = tid & 63, wv = tid >> 6;
  const int dl = tid >> 6, bb = tid & 63;

  if (bid < 64) {
    if (t <= 197) {
      const int d = bid*8 + dl;
      stage64(h0rd, TILE, wv, lane);
      __syncthreads();
      wave_dots(TILE, W_hh0, b_hh0, GHX, bid, wv, lane);
      __syncthreads();
      const int tok = targets[bb*TT + (t + 1)];
      float gir = W_ih0[(size_t)d*VV + tok]          + b_ih0[d];
      float giz = W_ih0[(size_t)(DD + d)*VV + tok]   + b_ih0[DD + d];
      float gin = W_ih0[(size_t)(2*DD + d)*VV + tok] + b_ih0[2*DD + d];
      float r_ = sigmoidf_(gir + GHX[(0*8 + dl)*64 + bb]);
      float z_ = sigmoidf_(giz + GHX[(1*8 + dl)*64 + bb]);
      float n_ = tanhf(gin + r_*GHX[(2*8 + dl)*64 + bb]);
      float h0old = TILE[bb*516 + d];
      h0wr[(size_t)bb*DD + d] = (1.f - z_)*n_ + z_*h0old;
    }
  } else if (bid < 128) {
    const int w_id = bid - 64;
    const int d = w_id*8 + dl;
    stage64(h1src, TILE, wv, lane);
    __syncthreads();
    wave_dots(TILE, W_hh1, b_hh1, GHX, w_id, wv, lane);
    float h1old = TILE[bb*516 + d];
    __syncthreads();
    float gir = gird[(size_t)(0*DD + d)*64 + bb];
    float giz = gird[(size_t)(1*DD + d)*64 + bb];
    float gin = gird[(size_t)(2*DD + d)*64 + bb];
    float r_ = sigmoidf_(gir + GHX[(0*8 + dl)*64 + bb]);
    float z_ = sigmoidf_(giz + GHX[(1*8 + dl)*64 + bb]);
    float n_ = tanhf(gin + r_*GHX[(2*8 + dl)*64 + bb]);
    h1dst[(size_t)bb*DD + d] = (1.f - z_)*n_ + z_*h1old;
  } else {
    if (t <= 198) {
      stage64(h0rd, TILE, wv, lane);
      __syncthreads();
      wave_dots_g(TILE, W_ih1, b_ih1, giwr, bid - 128, wv, lane);
    }
  }
}

// ======= persistent chain: 192 blocks, 1 barrier/step, coherent h/gi traffic =======
__launch_bounds__(512, 1)
__global__ void k_chain_pers(const float* h_init, const int* targets,
                             const float* W_ih0, const float* W_hh0,
                             const float* b_ih0, const float* b_hh0,
                             const float* W_hh1, const float* b_hh1,
                             const float* W_ih1, const float* b_ih1,
                             float* h0b, float* gib, float* h1a,
                             unsigned* gslot, unsigned* gbf) {
  __shared__ float SM[34560];
  float* const TILE = SM;
  float* const GHX  = SM + 33024;
  const int tid = threadIdx.x, bid = blockIdx.x;
  const int lane = tid & 63, wv = tid >> 6;
  const int dl = tid >> 6, bb = tid & 63;

  for (int t = 0; t < TT; ++t) {
    const float* h0rd = h0b + (size_t)((t + 1) & 1)*BBDD;
    float*       h0wr = h0b + (size_t)(t & 1)*BBDD;
    const float* h1src= (t == 0) ? (h_init + BBDD) : (h1a + (size_t)(t - 1)*BBDD);
    float*       h1dst= h1a + (size_t)t*BBDD;
    const float* gird = gib + (size_t)(t & 1)*(1536*64);
    float*       giwr = gib + (size_t)((t + 1) & 1)*(1536*64);

    if (bid < 64) {
      if (t <= 197) {
        const int d = bid*8 + dl;
        stage64_coh(h0rd, TILE, tid);
        __syncthreads();
        wave_dots(TILE, W_hh0, b_hh0, GHX, bid, wv, lane);
        __syncthreads();
        const int tok = targets[bb*TT + (t + 1)];
        float gir = W_ih0[(size_t)d*VV + tok]          + b_ih0[d];
        float giz = W_ih0[(size_t)(DD + d)*VV + tok]   + b_ih0[DD + d];
        float gin = W_ih0[(size_t)(2*DD + d)*VV + tok] + b_ih0[2*DD + d];
        float r_ = sigmoidf_(gir + GHX[(0*8 + dl)*64 + bb]);
        float z_ = sigmoidf_(giz + GHX[(1*8 + dl)*64 + bb]);
        float n_ = tanhf(gin + r_*GHX[(2*8 + dl)*64 + bb]);
        float h0old = TILE[bb*516 + d];
        coh_store1(&h0wr[(size_t)bb*DD + d], (1.f - z_)*n_ + z_*h0old);
      }
    } else if (bid < 128) {
      const int w_id = bid - 64;
      const int d = w_id*8 + dl;
      stage64_coh(h1src, TILE, tid);
      __syncthreads();
      wave_dots(TILE, W_hh1, b_hh1, GHX, w_id, wv, lane);
      float h1old = TILE[bb*516 + d];
      __syncthreads();
      float gir, giz, gin;
      coh_load3(&gird[(size_t)(0*DD + d)*64 + bb],
                &gird[(size_t)(1*DD + d)*64 + bb],
                &gird[(size_t)(2*DD + d)*64 + bb], gir, giz, gin);
      float r_ = sigmoidf_(gir + GHX[(0*8 + dl)*64 + bb]);
      float z_ = sigmoidf_(giz + GHX[(1*8 + dl)*64 + bb]);
      float n_ = tanhf(gin + r_*GHX[(2*8 + dl)*64 + bb]);
      coh_store1(&h1dst[(size_t)bb*DD + d], (1.f - z_)*n_ + z_*h1old);
    } else {
      if (t <= 198) {
        stage64_coh(h0rd, TILE, tid);
        __syncthreads();
        wave_dots_g_coh(TILE, W_ih1, b_ih1, giwr, bid - 128, wv, lane);
      }
    }
    gridbar(gslot, gbf, bid, tid, (unsigned)(t + 1));
  }
}

// ======= batched attention (conflict-free stride-1 f4 mapping) =======
__launch_bounds__(512, 1)
__global__ void k_attn_all(const float* __restrict__ h1a, const float* __restrict__ mem,
                           float* __restrict__ call) {
  __shared__ float SM[2*16*520 + 8*80];   // MT dbuf + SCR[8][5][16]
  float* const SCR = SM + 2*16*520;
  const int tid = threadIdx.x, bid = blockIdx.x;
  const int lane = tid & 63, wv = tid >> 6;
  const int b  = bid / 5;
  const int tt = bid % 5;
  const int r0 = wv*5;

  // Q rows in registers: lane owns d-slices [4L,4L+4) and [256+4L,256+4L+4)
  f4 qa[5], qb[5];
  size_t rbase[5];
  #pragma unroll
  for (int r = 0; r < 5; ++r) {
    rbase[r] = ((size_t)(tt*40 + r0 + r)*BB + b)*DD;
    qa[r] = *(const f4*)(h1a + rbase[r] + lane*4);
    qb[r] = *(const f4*)(h1a + rbase[r] + lane*4 + 256);
  }
  f4 aa[5], ab[5];
  float m[5], l[5];
  #pragma unroll
  for (int r = 0; r < 5; ++r) { aa[r] = (f4)0.f; ab[r] = (f4)0.f; m[r] = -3e38f; l[r] = 0.f; }

  const float* msrc = mem + (size_t)b*SS*DD;
  #pragma unroll
  for (int rr = 0; rr < 2; ++rr) {
    const int row = wv*2 + rr;
    const float* g = msrc + (size_t)row*DD + lane*4;
    gl_lds16(g,       SM + row*520);
    gl_lds16(g + 256, SM + row*520 + 256);
  }
  __syncthreads();

  int buf = 0;
  for (int tl = 0; tl < 64; ++tl) {
    if (tl + 1 < 64) {
      float* nb = SM + (buf^1)*16*520;
      #pragma unroll
      for (int rr = 0; rr < 2; ++rr) {
        const int row = wv*2 + rr;
        const float* g = msrc + (size_t)(tl+1)*16*DD + (size_t)row*DD + lane*4;
        gl_lds16(g,       nb + row*520);
        gl_lds16(g + 256, nb + row*520 + 256);
      }
    }
    const float* mt = SM + buf*16*520;

    // pass 1: scores -> SCR (stride-1 f4 reads: conflict-free)
    for (int s = 0; s < 16; ++s) {
      const f4 ma = *(const f4*)&mt[s*520 + lane*4];
      const f4 mb = *(const f4*)&mt[s*520 + lane*4 + 256];
      float p[5];
      #pragma unroll
      for (int r = 0; r < 5; ++r) p[r] = dot4(ma, qa[r]) + dot4(mb, qb[r]);
      #pragma unroll
      for (int off = 32; off; off >>= 1) {
        #pragma unroll
        for (int r = 0; r < 5; ++r) p[r] += __shfl_xor(p[r], off);
      }
      if (lane == 0) {
        #pragma unroll
        for (int r = 0; r < 5; ++r) SCR[wv*80 + r*16 + s] = p[r];
      }
    }
    // pass 2: per-row tile max, rescale, accumulate
    float mnew[5], esc[5];
    #pragma unroll
    for (int r = 0; r < 5; ++r) {
      float mx = -3e38f;
      #pragma unroll
      for (int s = 0; s < 16; ++s) mx = fmaxf(mx, SCR[wv*80 + r*16 + s]);
      mnew[r] = fmaxf(m[r], mx);
      esc[r]  = __expf(m[r] - mnew[r]);
      aa[r] *= esc[r]; ab[r] *= esc[r]; l[r] *= esc[r];
      m[r] = mnew[r];
    }
    for (int s = 0; s < 16; ++s) {
      const f4 ma = *(const f4*)&mt[s*520 + lane*4];
      const f4 mb = *(const f4*)&mt[s*520 + lane*4 + 256];
      #pragma unroll
      for (int r = 0; r < 5; ++r) {
        const float w = __expf(SCR[wv*80 + r*16 + s] - m[r]);
        aa[r] += w*ma; ab[r] += w*mb; l[r] += w;
      }
    }
    __syncthreads();
    buf ^= 1;
  }

  #pragma unroll
  for (int r = 0; r < 5; ++r) {
    const float inv = 1.f / l[r];
    *(f4*)(call + rbase[r] + lane*4)       = aa[r]*inv;
    *(f4*)(call + rbase[r] + lane*4 + 256) = ab[r]*inv;
  }
}

// ======= output projection + logits =======
__launch_bounds__(512, 1)
__global__ void k_outproj(const float* __restrict__ call, const float* __restrict__ h1a,
                          const float* __restrict__ W_out, const float* __restrict__ W_tok,
                          const float* __restrict__ b_tok, float* __restrict__ out) {
  __shared__ float SM[4352 + 33024];       // XR[64][68] + AH[64][516]
  float* const XR = SM;
  float* const AH = SM + 4352;
  const int tid = threadIdx.x, bid = blockIdx.x;
  const int lane = tid & 63, wv = tid >> 6;
  const int rowbase = bid * 64;

  float acc[8][8];
  #pragma unroll
  for (int r = 0; r < 8; ++r)
    #pragma unroll
    for (int j = 0; j < 8; ++j) acc[r][j] = 0.f;

  for (int kc = 0; kc < 16; ++kc) {
    __syncthreads();
    {
      const int row = tid >> 3;
      const int kp  = (tid & 7) * 8;
      const int k   = kc*64 + kp;
      const size_t grow = (size_t)(rowbase + row) * DD;
      const float* src = (k < DD) ? (call + grow + k) : (h1a + grow + (k - DD));
      f4 v0 = *(const f4*)src;
      f4 v1 = *(const f4*)(src + 4);
      *(f4*)&XR[row*68 + kp]     = v0;
      *(f4*)&XR[row*68 + kp + 4] = v1;
    }
    __syncthreads();
    for (int k4 = 0; k4 < 16; ++k4) {
      f4 w4[8];
      #pragma unroll
      for (int j = 0; j < 8; ++j)
        w4[j] = *(const f4*)&W_out[(size_t)(lane*8 + j)*(2*DD) + kc*64 + k4*4];
      #pragma unroll
      for (int r = 0; r < 8; ++r) {
        const f4 x4 = *(const f4*)&XR[(wv*8 + r)*68 + k4*4];
        #pragma unroll
        for (int j = 0; j < 8; ++j) acc[r][j] += dot4(x4, w4[j]);
      }
    }
  }
  #pragma unroll
  for (int r = 0; r < 8; ++r) {
    f4 t0, t1;
    t0.x = tanhf(acc[r][0]); t0.y = tanhf(acc[r][1]); t0.z = tanhf(acc[r][2]); t0.w = tanhf(acc[r][3]);
    t1.x = tanhf(acc[r][4]); t1.y = tanhf(acc[r][5]); t1.z = tanhf(acc[r][6]); t1.w = tanhf(acc[r][7]);
    *(f4*)&AH[(wv*8 + r)*516 + lane*8]     = t0;
    *(f4*)&AH[(wv*8 + r)*516 + lane*8 + 4] = t1;
  }
  __syncthreads();
  const int v = tid & 31;
  const int rq = tid >> 5;
  if (v < VV) {
    for (int it = 0; it < 4; ++it) {
      const int row = rq + it*16;
      float s = 0.f;
      const f4* ar = (const f4*)&AH[row*516];
      const f4* wt = (const f4*)&W_tok[(size_t)v*DD];
      #pragma unroll 4
      for (int k4 = 0; k4 < 128; ++k4) s += dot4(ar[k4], wt[k4]);
      const int gr = rowbase + row;
      const int t = gr >> 6, b = gr & 63;
      out[((size_t)b*TT + t)*VV + v] = s + b_tok[v];
    }
  }
}

extern "C" void kernel_launch(void* const* d_in, const int* in_sizes, int n_in,
                              void* d_out, int out_size, void* d_ws, size_t ws_size,
                              hipStream_t stream) {
  const float* h_init = (const float*)d_in[0];
  const int*   targets= (const int*)d_in[1];
  const float* mem    = (const float*)d_in[2];
  const float* W_ih0  = (const float*)d_in[3];
  const float* W_hh0  = (const float*)d_in[4];
  const float* b_ih0  = (const float*)d_in[5];
  const float* b_hh0  = (const float*)d_in[6];
  const float* W_ih1  = (const float*)d_in[7];
  const float* W_hh1  = (const float*)d_in[8];
  const float* b_ih1  = (const float*)d_in[9];
  const float* b_hh1  = (const float*)d_in[10];
  const float* W_out  = (const float*)d_in[11];
  const float* W_tok  = (const float*)d_in[12];
  const float* b_tok  = (const float*)d_in[13];
  float* out = (float*)d_out;
  float* ws  = (float*)d_ws;

  unsigned* gslot = (unsigned*)ws + WS_GSLOT;
  unsigned* gbf   = (unsigned*)ws + WS_GBF;
  float* h0b  = ws + WS_H0;
  float* gib  = ws + WS_GI;
  float* h1a  = ws + WS_H1A;
  float* call = ws + WS_CALL;

  hipMemsetAsync(d_ws, 0, WS_SLOTS_UINTS * sizeof(unsigned), stream);

  // prologue: h0(0); then {h0(1) | GI1(0)}
  hipLaunchKernelGGL(k_gru0, dim3(64), dim3(512), 0, stream,
                     h_init, targets, W_ih0, W_hh0, b_ih0, b_hh0, h0b, 0);
  hipLaunchKernelGGL(k_pro1, dim3(128), dim3(512), 0, stream,
                     h0b, targets, W_ih0, W_hh0, b_ih0, b_hh0,
                     W_ih1, b_ih1, h0b + BBDD, gib);

  // chain: persistent cooperative (fallback: 200 per-step launches)
  {
    void* args[] = { (void*)&h_init, (void*)&targets,
                     (void*)&W_ih0, (void*)&W_hh0, (void*)&b_ih0, (void*)&b_hh0,
                     (void*)&W_hh1, (void*)&b_hh1, (void*)&W_ih1, (void*)&b_ih1,
                     (void*)&h0b, (void*)&gib, (void*)&h1a,
                     (void*)&gslot, (void*)&gbf };
    hipError_t err = hipLaunchCooperativeKernel((const void*)k_chain_pers,
                                                dim3(CNBLK), dim3(512), args, 0, stream);
    if (err != hipSuccess) {
      for (int t = 0; t < TT; ++t) {
        const float* h0rd = h0b + (size_t)((t + 1) & 1)*BBDD;
        float*       h0wr = h0b + (size_t)(t & 1)*BBDD;
        const float* h1src= (t == 0) ? (h_init + BBDD) : (h1a + (size_t)(t - 1)*BBDD);
        float*       h1dst= h1a + (size_t)t*BBDD;
        const float* gird = gib + (size_t)(t & 1)*(1536*64);
        float*       giwr = gib + (size_t)((t + 1) & 1)*(1536*64);
        hipLaunchKernelGGL(k_chain, dim3(192), dim3(512), 0, stream,
                           h0rd, h0wr, h1src, h1dst, gird, giwr, targets,
                           W_ih0, W_hh0, b_ih0, b_hh0, W_hh1, b_hh1, W_ih1, b_ih1, t);
      }
    }
  }

  // batched attention over all 200 steps
  hipLaunchKernelGGL(k_attn_all, dim3(320), dim3(512), 0, stream, h1a, mem, call);

  // output projection + logits
  hipLaunchKernelGGL(k_outproj, dim3(200), dim3(512), 0, stream,
                     call, h1a, W_out, W_tok, b_tok, out);
}

// Round 11
// 4649.973 us; speedup vs baseline: 1.7224x; 1.7224x over previous
//
#include <hip/hip_runtime.h>

#define TT 200
#define SS 1024
#define DD 512
#define VV 30
#define BB 64
#define BBDD (BB*DD)              // 32768

// ---- ws float offsets (r9 layout) ----
#define WS_H0   0                         // [2][64][512]
#define WS_GI   (2*BBDD)                  // [2][1536][64]
#define WS_H1A  (WS_GI + 2*1536*64)       // [200][64][512]
#define WS_CALL (WS_H1A + 200*BBDD)       // [200][64][512]

typedef __attribute__((ext_vector_type(4))) float f4;

__device__ __forceinline__ float dot4(f4 a, f4 b) {
  return a.x*b.x + a.y*b.y + a.z*b.z + a.w*b.w;
}
__device__ __forceinline__ float sigmoidf_(float x) { return 1.f/(1.f + __expf(-x)); }

__device__ __forceinline__ void gl_lds16(const void* g, void* l) {
  __builtin_amdgcn_global_load_lds(
      (const __attribute__((address_space(1))) unsigned int*)g,
      (__attribute__((address_space(3))) unsigned int*)l,
      16, 0, 0);
}

// async global [64][512] -> LDS [64][516] ; follow with __syncthreads()
__device__ __forceinline__ void stage64(const float* src, float* TILE, int wv, int lane) {
  #pragma unroll
  for (int rr = 0; rr < 8; ++rr) {
    const int row = wv*8 + rr;
    const float* g = src + (size_t)row*DD + lane*4;
    gl_lds16(g,       TILE + row*516);
    gl_lds16(g + 256, TILE + row*516 + 256);
  }
}

// wave-column GRU dots into LOCAL gate buffer GH[24][64]
__device__ __forceinline__ void wave_dots(const float* TILE, const float* W, const float* bias,
                                          float* GH, int w_id, int wv, int lane) {
  const int c0 = wv*3, c1 = c0+1, c2 = c0+2;
  const int R0 = __builtin_amdgcn_readfirstlane(((c0>>3)<<9) + w_id*8 + (c0&7));
  const int R1 = __builtin_amdgcn_readfirstlane(((c1>>3)<<9) + w_id*8 + (c1&7));
  const int R2 = __builtin_amdgcn_readfirstlane(((c2>>3)<<9) + w_id*8 + (c2&7));
  const f4* w0 = (const f4*)(W + (size_t)R0*DD);
  const f4* w1 = (const f4*)(W + (size_t)R1*DD);
  const f4* w2 = (const f4*)(W + (size_t)R2*DD);
  const f4* hv4 = (const f4*)TILE + (size_t)lane*129;
  float a0=0.f, a1=0.f, a2=0.f;
  #pragma unroll 4
  for (int kq = 0; kq < 128; ++kq) {
    f4 h = hv4[kq];
    a0 += dot4(h, w0[kq]); a1 += dot4(h, w1[kq]); a2 += dot4(h, w2[kq]);
  }
  GH[c0*64 + lane] = a0 + bias[R0];
  GH[c1*64 + lane] = a1 + bias[R1];
  GH[c2*64 + lane] = a2 + bias[R2];
}

// wave-column dots writing GLOBAL gi buffer gi[(g*512+d)*64 + lane], bias included
__device__ __forceinline__ void wave_dots_g(const float* TILE, const float* W, const float* bias,
                                            float* gi, int w_id, int wv, int lane) {
  const int c0 = wv*3, c1 = c0+1, c2 = c0+2;
  const int R0 = __builtin_amdgcn_readfirstlane(((c0>>3)<<9) + w_id*8 + (c0&7));
  const int R1 = __builtin_amdgcn_readfirstlane(((c1>>3)<<9) + w_id*8 + (c1&7));
  const int R2 = __builtin_amdgcn_readfirstlane(((c2>>3)<<9) + w_id*8 + (c2&7));
  const f4* w0 = (const f4*)(W + (size_t)R0*DD);
  const f4* w1 = (const f4*)(W + (size_t)R1*DD);
  const f4* w2 = (const f4*)(W + (size_t)R2*DD);
  const f4* hv4 = (const f4*)TILE + (size_t)lane*129;
  float a0=0.f, a1=0.f, a2=0.f;
  #pragma unroll 4
  for (int kq = 0; kq < 128; ++kq) {
    f4 h = hv4[kq];
    a0 += dot4(h, w0[kq]); a1 += dot4(h, w1[kq]); a2 += dot4(h, w2[kq]);
  }
  gi[(size_t)R0*64 + lane] = a0 + bias[R0];
  gi[(size_t)R1*64 + lane] = a1 + bias[R1];
  gi[(size_t)R2*64 + lane] = a2 + bias[R2];
}

// ================= prologue 1: h0(0) =================
__launch_bounds__(512, 1)
__global__ void k_gru0(const float* __restrict__ h0prev, const int* __restrict__ targets,
                       const float* __restrict__ W_ih0, const float* __restrict__ W_hh0,
                       const float* __restrict__ b_ih0, const float* __restrict__ b_hh0,
                       float* __restrict__ h0out, int tokcol) {
  __shared__ float SM[34560];
  float* const TILE = SM;
  float* const GHX  = SM + 33024;
  const int tid = threadIdx.x, bid = blockIdx.x;
  const int lane = tid & 63, wv = tid >> 6;
  stage64(h0prev, TILE, wv, lane);
  __syncthreads();
  wave_dots(TILE, W_hh0, b_hh0, GHX, bid, wv, lane);
  __syncthreads();
  const int dl = tid >> 6, bb = tid & 63, d = bid*8 + dl;
  const int tok = targets[bb*TT + tokcol];
  float gir = W_ih0[(size_t)d*VV + tok]          + b_ih0[d];
  float giz = W_ih0[(size_t)(DD + d)*VV + tok]   + b_ih0[DD + d];
  float gin = W_ih0[(size_t)(2*DD + d)*VV + tok] + b_ih0[2*DD + d];
  float r_ = sigmoidf_(gir + GHX[(0*8 + dl)*64 + bb]);
  float z_ = sigmoidf_(giz + GHX[(1*8 + dl)*64 + bb]);
  float n_ = tanhf(gin + r_*GHX[(2*8 + dl)*64 + bb]);
  float h0old = TILE[bb*516 + d];
  h0out[(size_t)bb*DD + d] = (1.f - z_)*n_ + z_*h0old;
}

// ================= prologue 2: h0(1) [0..63] | GI1(0) [64..127] =================
__launch_bounds__(512, 1)
__global__ void k_pro1(const float* __restrict__ h0buf0, const int* __restrict__ targets,
                       const float* __restrict__ W_ih0, const float* __restrict__ W_hh0,
                       const float* __restrict__ b_ih0, const float* __restrict__ b_hh0,
                       const float* __restrict__ W_ih1, const float* __restrict__ b_ih1,
                       float* __restrict__ h0buf1, float* __restrict__ gibuf0) {
  __shared__ float SM[34560];
  float* const TILE = SM;
  float* const GHX  = SM + 33024;
  const int tid = threadIdx.x, bid = blockIdx.x;
  const int lane = tid & 63, wv = tid >> 6;
  stage64(h0buf0, TILE, wv, lane);
  __syncthreads();
  if (bid < 64) {
    wave_dots(TILE, W_hh0, b_hh0, GHX, bid, wv, lane);
    __syncthreads();
    const int dl = tid >> 6, bb = tid & 63, d = bid*8 + dl;
    const int tok = targets[bb*TT + 0];
    float gir = W_ih0[(size_t)d*VV + tok]          + b_ih0[d];
    float giz = W_ih0[(size_t)(DD + d)*VV + tok]   + b_ih0[DD + d];
    float gin = W_ih0[(size_t)(2*DD + d)*VV + tok] + b_ih0[2*DD + d];
    float r_ = sigmoidf_(gir + GHX[(0*8 + dl)*64 + bb]);
    float z_ = sigmoidf_(giz + GHX[(1*8 + dl)*64 + bb]);
    float n_ = tanhf(gin + r_*GHX[(2*8 + dl)*64 + bb]);
    float h0old = TILE[bb*516 + d];
    h0buf1[(size_t)bb*DD + d] = (1.f - z_)*n_ + z_*h0old;
  } else {
    wave_dots_g(TILE, W_ih1, b_ih1, gibuf0, bid - 64, wv, lane);
  }
}

// ======= chain: h0(t+2) [0..63] | h1(t) [64..127] | GI1(t+1) [128..191] =======
__launch_bounds__(512, 1)
__global__ void k_chain(const float* __restrict__ h0rd, float* __restrict__ h0wr,
                        const float* __restrict__ h1src, float* __restrict__ h1dst,
                        const float* __restrict__ gird, float* __restrict__ giwr,
                        const int* __restrict__ targets,
                        const float* __restrict__ W_ih0, const float* __restrict__ W_hh0,
                        const float* __restrict__ b_ih0, const float* __restrict__ b_hh0,
                        const float* __restrict__ W_hh1, const float* __restrict__ b_hh1,
                        const float* __restrict__ W_ih1, const float* __restrict__ b_ih1,
                        int t) {
  __shared__ float SM[34560];
  float* const TILE = SM;
  float* const GHX  = SM + 33024;
  const int tid = threadIdx.x, bid = blockIdx.x;
  const int lane = tid & 63, wv = tid >> 6;
  const int dl = tid >> 6, bb = tid & 63;

  if (bid < 64) {
    if (t <= 197) {
      const int d = bid*8 + dl;
      stage64(h0rd, TILE, wv, lane);
      __syncthreads();
      wave_dots(TILE, W_hh0, b_hh0, GHX, bid, wv, lane);
      __syncthreads();
      const int tok = targets[bb*TT + (t + 1)];
      float gir = W_ih0[(size_t)d*VV + tok]          + b_ih0[d];
      float giz = W_ih0[(size_t)(DD + d)*VV + tok]   + b_ih0[DD + d];
      float gin = W_ih0[(size_t)(2*DD + d)*VV + tok] + b_ih0[2*DD + d];
      float r_ = sigmoidf_(gir + GHX[(0*8 + dl)*64 + bb]);
      float z_ = sigmoidf_(giz + GHX[(1*8 + dl)*64 + bb]);
      float n_ = tanhf(gin + r_*GHX[(2*8 + dl)*64 + bb]);
      float h0old = TILE[bb*516 + d];
      h0wr[(size_t)bb*DD + d] = (1.f - z_)*n_ + z_*h0old;
    }
  } else if (bid < 128) {
    const int w_id = bid - 64;
    const int d = w_id*8 + dl;
    stage64(h1src, TILE, wv, lane);
    __syncthreads();
    wave_dots(TILE, W_hh1, b_hh1, GHX, w_id, wv, lane);
    float h1old = TILE[bb*516 + d];
    __syncthreads();
    float gir = gird[(size_t)(0*DD + d)*64 + bb];
    float giz = gird[(size_t)(1*DD + d)*64 + bb];
    float gin = gird[(size_t)(2*DD + d)*64 + bb];
    float r_ = sigmoidf_(gir + GHX[(0*8 + dl)*64 + bb]);
    float z_ = sigmoidf_(giz + GHX[(1*8 + dl)*64 + bb]);
    float n_ = tanhf(gin + r_*GHX[(2*8 + dl)*64 + bb]);
    h1dst[(size_t)bb*DD + d] = (1.f - z_)*n_ + z_*h1old;
  } else {
    if (t <= 198) {
      stage64(h0rd, TILE, wv, lane);
      __syncthreads();
      wave_dots_g(TILE, W_ih1, b_ih1, giwr, bid - 128, wv, lane);
    }
  }
}

// ======= batched attention: 4-lane-slice scores, 2-shfl reduce, Q in LDS =======
// block = (b, 40-row t-chunk); 16-row mem tiles double-buffered.
// LDS: MT[2][16*516]=16512 | QL[40*516]=20640 | SCR[8][5][16]=640  -> 37792 floats (151KB)
__launch_bounds__(512, 1)
__global__ void k_attn_all(const float* __restrict__ h1a, const float* __restrict__ mem,
                           float* __restrict__ call) {
  __shared__ float SM[37792];
  float* const QL  = SM + 16512;
  float* const SCR = SM + 37152;
  const int tid = threadIdx.x, bid = blockIdx.x;
  const int lane = tid & 63, wv = tid >> 6;
  const int b = bid / 5, tt = bid % 5;
  const int g = lane >> 2, sub = lane & 3;

  // stage Q rows (each wave stages its own 5 q-rows)
  #pragma unroll
  for (int rr = 0; rr < 5; ++rr) {
    const int row = wv*5 + rr;
    const float* src = h1a + ((size_t)(tt*40 + row)*BB + b)*DD + lane*4;
    gl_lds16(src,       QL + row*516);
    gl_lds16(src + 256, QL + row*516 + 256);
  }
  // stage mem tile 0
  const float* msrc = mem + (size_t)b*SS*DD;
  #pragma unroll
  for (int rr = 0; rr < 2; ++rr) {
    const int row = wv*2 + rr;
    const float* gsp = msrc + (size_t)row*DD + lane*4;
    gl_lds16(gsp,       SM + row*516);
    gl_lds16(gsp + 256, SM + row*516 + 256);
  }
  __syncthreads();

  f4 aa[5], ab[5]; float m[5], l[5];
  #pragma unroll
  for (int r = 0; r < 5; ++r) { aa[r] = (f4)0.f; ab[r] = (f4)0.f; m[r] = -3e38f; l[r] = 0.f; }

  int buf = 0;
  for (int tl = 0; tl < 64; ++tl) {
    if (tl + 1 < 64) {
      float* nb = SM + (buf^1)*8256;
      #pragma unroll
      for (int rr = 0; rr < 2; ++rr) {
        const int row = wv*2 + rr;
        const float* gsp = msrc + (size_t)(tl+1)*16*DD + (size_t)row*DD + lane*4;
        gl_lds16(gsp,       nb + row*516);
        gl_lds16(gsp + 256, nb + row*516 + 256);
      }
    }
    const f4* mtf4 = (const f4*)(SM + buf*8256);   // row stride 129 f4
    const f4* qlf4 = (const f4*)QL;

    // pass 1: lane (g,sub) computes 128-dim partial of score(q_r, s=g)
    float p[5] = {0.f, 0.f, 0.f, 0.f, 0.f};
    #pragma unroll 4
    for (int k = 0; k < 32; ++k) {
      const int idx = sub*32 + ((k + sub) & 31);   // sub-rotated: conflict-free
      const f4 mv = mtf4[g*129 + idx];
      #pragma unroll
      for (int r = 0; r < 5; ++r)
        p[r] += dot4(mv, qlf4[(wv*5 + r)*129 + idx]);
    }
    #pragma unroll
    for (int r = 0; r < 5; ++r) {
      p[r] += __shfl_xor(p[r], 1);
      p[r] += __shfl_xor(p[r], 2);
    }
    if (sub == 0) {
      #pragma unroll
      for (int r = 0; r < 5; ++r) SCR[wv*80 + r*16 + g] = p[r];
    }
    // (wave-internal LDS write->read; single instruction stream, compiler waits lgkmcnt)

    // pass 2: online softmax + PV (lane <-> dim, stride-1)
    #pragma unroll
    for (int r = 0; r < 5; ++r) {
      float mx = SCR[wv*80 + r*16];
      #pragma unroll
      for (int s = 1; s < 16; ++s) mx = fmaxf(mx, SCR[wv*80 + r*16 + s]);
      const float mnew = fmaxf(m[r], mx);
      const float esc = __expf(m[r] - mnew);
      aa[r] *= esc; ab[r] *= esc; l[r] *= esc;
      m[r] = mnew;
    }
    for (int s = 0; s < 16; ++s) {
      const f4 ma = mtf4[s*129 + lane];
      const f4 mb = mtf4[s*129 + lane + 64];
      #pragma unroll
      for (int r = 0; r < 5; ++r) {
        const float w = __expf(SCR[wv*80 + r*16 + s] - m[r]);
        aa[r] += w*ma; ab[r] += w*mb; l[r] += w;
      }
    }
    __syncthreads();
    buf ^= 1;
  }

  #pragma unroll
  for (int r = 0; r < 5; ++r) {
    const float inv = 1.f / l[r];
    float* dst = call + ((size_t)(tt*40 + wv*5 + r)*BB + b)*DD;
    *(f4*)(dst + lane*4)       = aa[r]*inv;
    *(f4*)(dst + lane*4 + 256) = ab[r]*inv;
  }
}

// ======= output projection + logits =======
__launch_bounds__(512, 1)
__global__ void k_outproj(const float* __restrict__ call, const float* __restrict__ h1a,
                          const float* __restrict__ W_out, const float* __restrict__ W_tok,
                          const float* __restrict__ b_tok, float* __restrict__ out) {
  __shared__ float SM[4352 + 33024];       // XR[64][68] + AH[64][516]
  float* const XR = SM;
  float* const AH = SM + 4352;
  const int tid = threadIdx.x, bid = blockIdx.x;
  const int lane = tid & 63, wv = tid >> 6;
  const int rowbase = bid * 64;

  float acc[8][8];
  #pragma unroll
  for (int r = 0; r < 8; ++r)
    #pragma unroll
    for (int j = 0; j < 8; ++j) acc[r][j] = 0.f;

  for (int kc = 0; kc < 16; ++kc) {
    __syncthreads();
    {
      const int row = tid >> 3;
      const int kp  = (tid & 7) * 8;
      const int k   = kc*64 + kp;
      const size_t grow = (size_t)(rowbase + row) * DD;
      const float* src = (k < DD) ? (call + grow + k) : (h1a + grow + (k - DD));
      f4 v0 = *(const f4*)src;
      f4 v1 = *(const f4*)(src + 4);
      *(f4*)&XR[row*68 + kp]     = v0;
      *(f4*)&XR[row*68 + kp + 4] = v1;
    }
    __syncthreads();
    for (int k4 = 0; k4 < 16; ++k4) {
      f4 w4[8];
      #pragma unroll
      for (int j = 0; j < 8; ++j)
        w4[j] = *(const f4*)&W_out[(size_t)(lane*8 + j)*(2*DD) + kc*64 + k4*4];
      #pragma unroll
      for (int r = 0; r < 8; ++r) {
        const f4 x4 = *(const f4*)&XR[(wv*8 + r)*68 + k4*4];
        #pragma unroll
        for (int j = 0; j < 8; ++j) acc[r][j] += dot4(x4, w4[j]);
      }
    }
  }
  #pragma unroll
  for (int r = 0; r < 8; ++r) {
    f4 t0, t1;
    t0.x = tanhf(acc[r][0]); t0.y = tanhf(acc[r][1]); t0.z = tanhf(acc[r][2]); t0.w = tanhf(acc[r][3]);
    t1.x = tanhf(acc[r][4]); t1.y = tanhf(acc[r][5]); t1.z = tanhf(acc[r][6]); t1.w = tanhf(acc[r][7]);
    *(f4*)&AH[(wv*8 + r)*516 + lane*8]     = t0;
    *(f4*)&AH[(wv*8 + r)*516 + lane*8 + 4] = t1;
  }
  __syncthreads();
  const int v = tid & 31;
  const int rq = tid >> 5;
  if (v < VV) {
    for (int it = 0; it < 4; ++it) {
      const int row = rq + it*16;
      float s = 0.f;
      const f4* ar = (const f4*)&AH[row*516];
      const f4* wt = (const f4*)&W_tok[(size_t)v*DD];
      #pragma unroll 4
      for (int k4 = 0; k4 < 128; ++k4) s += dot4(ar[k4], wt[k4]);
      const int gr = rowbase + row;
      const int t = gr >> 6, b = gr & 63;
      out[((size_t)b*TT + t)*VV + v] = s + b_tok[v];
    }
  }
}

extern "C" void kernel_launch(void* const* d_in, const int* in_sizes, int n_in,
                              void* d_out, int out_size, void* d_ws, size_t ws_size,
                              hipStream_t stream) {
  const float* h_init = (const float*)d_in[0];
  const int*   targets= (const int*)d_in[1];
  const float* mem    = (const float*)d_in[2];
  const float* W_ih0  = (const float*)d_in[3];
  const float* W_hh0  = (const float*)d_in[4];
  const float* b_ih0  = (const float*)d_in[5];
  const float* b_hh0  = (const float*)d_in[6];
  const float* W_ih1  = (const float*)d_in[7];
  const float* W_hh1  = (const float*)d_in[8];
  const float* b_ih1  = (const float*)d_in[9];
  const float* b_hh1  = (const float*)d_in[10];
  const float* W_out  = (const float*)d_in[11];
  const float* W_tok  = (const float*)d_in[12];
  const float* b_tok  = (const float*)d_in[13];
  float* out = (float*)d_out;
  float* ws  = (float*)d_ws;

  float* h0b  = ws + WS_H0;
  float* gib  = ws + WS_GI;
  float* h1a  = ws + WS_H1A;
  float* call = ws + WS_CALL;

  // prologue: h0(0); then {h0(1) | GI1(0)}
  hipLaunchKernelGGL(k_gru0, dim3(64), dim3(512), 0, stream,
                     h_init, targets, W_ih0, W_hh0, b_ih0, b_hh0, h0b, 0);
  hipLaunchKernelGGL(k_pro1, dim3(128), dim3(512), 0, stream,
                     h0b, targets, W_ih0, W_hh0, b_ih0, b_hh0,
                     W_ih1, b_ih1, h0b + BBDD, gib);

  // chain: L(t) -> h1(t), h0(t+2), GI1(t+1)  (per-step launches; proven)
  for (int t = 0; t < TT; ++t) {
    const float* h0rd = h0b + (size_t)((t + 1) & 1)*BBDD;
    float*       h0wr = h0b + (size_t)(t & 1)*BBDD;
    const float* h1src= (t == 0) ? (h_init + BBDD) : (h1a + (size_t)(t - 1)*BBDD);
    float*       h1dst= h1a + (size_t)t*BBDD;
    const float* gird = gib + (size_t)(t & 1)*(1536*64);
    float*       giwr = gib + (size_t)((t + 1) & 1)*(1536*64);
    hipLaunchKernelGGL(k_chain, dim3(192), dim3(512), 0, stream,
                       h0rd, h0wr, h1src, h1dst, gird, giwr, targets,
                       W_ih0, W_hh0, b_ih0, b_hh0, W_hh1, b_hh1, W_ih1, b_ih1, t);
  }

  // batched attention over all 200 steps
  hipLaunchKernelGGL(k_attn_all, dim3(320), dim3(512), 0, stream, h1a, mem, call);

  // output projection + logits
  hipLaunchKernelGGL(k_outproj, dim3(200), dim3(512), 0, stream,
                     call, h1a, W_out, W_tok, b_tok, out);
}